// Round 1
// baseline (475.057 us; speedup 1.0000x reference)
//
#include <hip/hip_runtime.h>
#include <math.h>

#define S 512
#define B 128
#define T 256
#define NT 1024

typedef _Float16 h2 __attribute__((ext_vector_type(2)));
typedef _Float16 h8 __attribute__((ext_vector_type(8)));

#if __has_builtin(__builtin_amdgcn_fdot2)
#define FDOT2(a, b, c) __builtin_amdgcn_fdot2((a), (b), (c), false)
#else
#define FDOT2(a, b, c) fmaf((float)(a)[0], (float)(b)[0], fmaf((float)(a)[1], (float)(b)[1], (c)))
#endif

#define AS1 __attribute__((address_space(1)))
#define AS3 __attribute__((address_space(3)))

// Raw barrier: LDS drain only (no vmcnt drain — ring prefetch stays in flight, T3/T4 pattern)
#define BAR() do { asm volatile("s_waitcnt lgkmcnt(0)" ::: "memory"); __builtin_amdgcn_s_barrier(); } while (0)

__global__ __launch_bounds__(NT, 4) void crf_fwd(
    const float* __restrict__ feats,
    const int*   __restrict__ tags,
    const int*   __restrict__ mask,
    const float* __restrict__ start_t,
    const float* __restrict__ end_t,
    const float* __restrict__ trans,
    float*       __restrict__ out)
{
    const int b    = blockIdx.x;
    const int tid  = threadIdx.x;
    const int j    = tid & (T - 1);   // output column
    const int q    = tid >> 8;        // i-segment 0..3 (64 rows each)
    const int lane = tid & 63;
    const int wid  = tid >> 6;

    __shared__ __attribute__((aligned(16))) _Float16 pl[T];  // p in fp16
    __shared__ float partial[NT];
    __shared__ float ftile[4][T];     // feats prefetch ring
    __shared__ int   msk[S];
    __shared__ float redmax[4];
    __shared__ float redg[8];
    __shared__ float redm[8];

    // ---- E fragment in registers: E[i][j]=exp(trans[i][j]), i in [q*64,q*64+64), fp16 pairs
    h2 Ereg[32];
    {
        const float* tp = trans + j;
        #pragma unroll
        for (int m = 0; m < 32; ++m) {
            const int i0 = q * 64 + 2 * m;
            float e0 = __expf(tp[(size_t)i0 * T]);
            float e1 = __expf(tp[(size_t)(i0 + 1) * T]);
            h2 v; v[0] = (_Float16)e0; v[1] = (_Float16)e1;
            Ereg[m] = v;
        }
    }

    // ---- mask column preload
    if (tid < S) msk[tid] = mask[tid * B + b];

    // ---- gold-score terms: one thread per time step
    float gterm = 0.f;
    float mcnt  = 0.f;
    if (tid < S) {
        const int t  = tid;
        const int tg = tags[t * B + b];
        const float emit = feats[((size_t)t * B + b) * T + tg];
        const int m = mask[t * B + b];
        mcnt = (float)m;
        if (t == 0) {
            gterm = start_t[tg] + emit;
        } else {
            const int tgp = tags[(t - 1) * B + b];
            gterm = m ? (emit + trans[tgp * T + tg]) : 0.f;
        }
    }
    #pragma unroll
    for (int o = 32; o > 0; o >>= 1) {
        gterm += __shfl_down(gterm, o, 64);
        mcnt  += __shfl_down(mcnt, o, 64);
    }
    if (tid < S && lane == 0) { redg[wid] = gterm; redm[wid] = mcnt; }

    // ---- score init (t=0) + initial max
    float vv = 0.f;
    if (tid < T) vv = start_t[j] + feats[(size_t)b * T + j];
    {
        float mx = (tid < T) ? vv : -3.0e38f;
        #pragma unroll
        for (int o = 32; o > 0; o >>= 1) mx = fmaxf(mx, __shfl_xor(mx, o, 64));
        if (tid < T && lane == 0) redmax[wid] = mx;
    }

    // ---- prime prefetch ring with feats tiles t=1..3
    if (tid >= T && tid < 2 * T) {
        const int jj = tid - T;
        #pragma unroll
        for (int tn = 1; tn <= 3; ++tn) {
            const float* src = feats + ((size_t)tn * B + b) * T + jj;
            __builtin_amdgcn_global_load_lds((const AS1 void*)src,
                                             (AS3 void*)&ftile[tn & 3][jj], 4, 0, 0);
        }
    }

    __syncthreads();   // one full drain (init only)

    float gold = 0.f;
    if (tid == 0) {
        float g = 0.f, mc = 0.f;
        #pragma unroll
        for (int w = 0; w < 8; ++w) { g += redg[w]; mc += redm[w]; }
        const int seq_end = (int)mc - 1;
        const int lt = tags[seq_end * B + b];
        gold = g + end_t[lt];
    }

    float M = 0.f;
    for (int t = 1; t < S; ++t) {
        // phase B: p = exp(score - M); waves 4-7 issue ring prefetch for t+3
        if (tid < T) {
            M = fmaxf(fmaxf(redmax[0], redmax[1]), fmaxf(redmax[2], redmax[3]));
            const float p = __expf(vv - M);
            pl[j] = (_Float16)p;
        } else if (tid < 2 * T) {
            const int tn = t + 3;
            if (tn < S) {
                const int jj = tid - T;
                const float* src = feats + ((size_t)tn * B + b) * T + jj;
                __builtin_amdgcn_global_load_lds((const AS1 void*)src,
                                                 (AS3 void*)&ftile[tn & 3][jj], 4, 0, 0);
            }
        }
        BAR();   // barrier 1: pl visible

        // GEMV: acc = sum over this thread's 64-row segment of p[i]*E[i][j]
        float acc = 0.f;
        {
            const h8* pp = (const h8*)(pl + (q << 6));
            #pragma unroll
            for (int r = 0; r < 8; ++r) {
                const h8 pv = pp[r];                       // 16B broadcast ds_read
                const h2 b0 = __builtin_shufflevector(pv, pv, 0, 1);
                const h2 b1 = __builtin_shufflevector(pv, pv, 2, 3);
                const h2 b2 = __builtin_shufflevector(pv, pv, 4, 5);
                const h2 b3 = __builtin_shufflevector(pv, pv, 6, 7);
                acc = FDOT2(Ereg[4 * r + 0], b0, acc);
                acc = FDOT2(Ereg[4 * r + 1], b1, acc);
                acc = FDOT2(Ereg[4 * r + 2], b2, acc);
                acc = FDOT2(Ereg[4 * r + 3], b3, acc);
            }
        }
        partial[tid] = acc;
        asm volatile("s_waitcnt vmcnt(3)" ::: "memory");   // tile t landed (3-step slack)
        BAR();   // barrier 2: partials visible

        // phase D: combine partials, log, masked update, next-step max
        if (tid < T) {
            const float s = partial[j] + partial[T + j] + partial[2 * T + j] + partial[3 * T + j];
            const float nxt = ftile[t & 3][j] + M + __logf(s);
            vv = msk[t] ? nxt : vv;
            float mx = vv;
            #pragma unroll
            for (int o = 32; o > 0; o >>= 1) mx = fmaxf(mx, __shfl_xor(mx, o, 64));
            if (lane == 0) redmax[wid] = mx;
        }
        BAR();   // barrier 3: redmax visible, buffers reusable
    }

    // ---- finalize: forward = logsumexp(score + end_transitions)
    float u = -3.0e38f;
    if (tid < T) u = vv + end_t[j];
    {
        float mx = u;
        #pragma unroll
        for (int o = 32; o > 0; o >>= 1) mx = fmaxf(mx, __shfl_xor(mx, o, 64));
        if (tid < T && lane == 0) redmax[wid] = mx;
    }
    BAR();
    if (tid < T) {
        const float M3 = fmaxf(fmaxf(redmax[0], redmax[1]), fmaxf(redmax[2], redmax[3]));
        float e = __expf(u - M3);
        #pragma unroll
        for (int o = 32; o > 0; o >>= 1) e += __shfl_xor(e, o, 64);
        if (lane == 0) partial[wid] = e;
    }
    BAR();
    if (tid == 0) {
        const float ssum = partial[0] + partial[1] + partial[2] + partial[3];
        const float M3 = fmaxf(fmaxf(redmax[0], redmax[1]), fmaxf(redmax[2], redmax[3]));
        out[b] = M3 + __logf(ssum) - gold;
    }
}

extern "C" void kernel_launch(void* const* d_in, const int* in_sizes, int n_in,
                              void* d_out, int out_size, void* d_ws, size_t ws_size,
                              hipStream_t stream) {
    const float* feats  = (const float*)d_in[0];
    const int*   tags   = (const int*)d_in[1];
    const int*   mask   = (const int*)d_in[2];
    const float* startt = (const float*)d_in[3];
    const float* endt   = (const float*)d_in[4];
    const float* transt = (const float*)d_in[5];
    float* out = (float*)d_out;
    crf_fwd<<<dim3(B), dim3(NT), 0, stream>>>(feats, tags, mask, startt, endt, transt, out);
}